// Round 4
// baseline (495.403 us; speedup 1.0000x reference)
//
#include <hip/hip_runtime.h>

// Problem constants (from reference)
#define NL0 300000
#define NL1 60000
#define NL2 15000
#define NL3 4000
#define NE0 960000
#define NE1 240000
#define NE2 64000
#define E_ALL (NE0 + NE1 + NE2)
#define F_IN 256
#define F_HID 128
#define F_OUT 47

// Layer-0 src 4-way blocking (L3 residency): bucket = #thresholds passed
#define SPLIT0 4
#define B0 75000
// Virtual CSR row layout (concatenated across layers):
//   [0, 240000)          : layer0, vrow = dst*4 + bucket(src)
//   [240000, 255000)     : layer1, row = 240000 + dst
//   [255000, 259000)     : layer2, row = 255000 + dst
#define RBASE1 (NL1 * SPLIT0)
#define RBASE2 (RBASE1 + NL2)
#define NROWS (RBASE2 + NL3)

__device__ inline int bucket0(int s) {
    return (s >= B0) + (s >= 2 * B0) + (s >= 3 * B0);
}

// ---------------------------------------------------------------------------
// Wave-wide (64-lane) inclusive scan
// ---------------------------------------------------------------------------
__device__ inline int wave_incl_scan(int v) {
    int lane = threadIdx.x & 63;
#pragma unroll
    for (int off = 1; off < 64; off <<= 1) {
        int t = __shfl_up(v, off, 64);
        if (lane >= off) v += t;
    }
    return v;
}

// ---------------------------------------------------------------------------
// Fused histogram over all three layers' edges
// ---------------------------------------------------------------------------
__global__ void histogram_all(const int* __restrict__ src0, const int* __restrict__ dst0,
                              const int* __restrict__ dst1, const int* __restrict__ dst2,
                              int* __restrict__ cnt) {
    int i = blockIdx.x * blockDim.x + threadIdx.x;
    if (i >= E_ALL) return;
    int k;
    if (i < NE0) {
        k = dst0[i] * SPLIT0 + bucket0(src0[i]);
    } else if (i < NE0 + NE1) {
        k = RBASE1 + dst1[i - NE0];
    } else {
        k = RBASE2 + dst2[i - NE0 - NE1];
    }
    atomicAdd(&cnt[k], 1);
}

// ---------------------------------------------------------------------------
// Exclusive scan over NROWS counters (chunked: per-1024 scan + totals + add)
// ---------------------------------------------------------------------------
__global__ __launch_bounds__(1024) void scan_block(const int* __restrict__ cnt, int N,
                                                   int* __restrict__ row_start,
                                                   int* __restrict__ blocksum) {
    __shared__ int wsum[16];
    int i = blockIdx.x * 1024 + threadIdx.x;
    int lane = threadIdx.x & 63, wid = threadIdx.x >> 6;
    int v = (i < N) ? cnt[i] : 0;
    int incl = wave_incl_scan(v);
    if (lane == 63) wsum[wid] = incl;
    __syncthreads();
    if (threadIdx.x < 16) {
        int w = wsum[threadIdx.x];
#pragma unroll
        for (int off = 1; off < 16; off <<= 1) {
            int t = __shfl_up(w, off, 64);
            if ((int)threadIdx.x >= off) w += t;
        }
        wsum[threadIdx.x] = w;
    }
    __syncthreads();
    int woff = wid ? wsum[wid - 1] : 0;
    if (i < N) row_start[i] = woff + incl - v;
    if (threadIdx.x == 0) blocksum[blockIdx.x] = wsum[15];
}

__global__ __launch_bounds__(1024) void scan_totals(int* __restrict__ bs, int nb) {
    __shared__ int wsum[16];
    int i = threadIdx.x;
    int lane = i & 63, wid = i >> 6;
    int v = (i < nb) ? bs[i] : 0;
    int incl = wave_incl_scan(v);
    if (lane == 63) wsum[wid] = incl;
    __syncthreads();
    if (i < 16) {
        int w = wsum[i];
#pragma unroll
        for (int off = 1; off < 16; off <<= 1) {
            int t = __shfl_up(w, off, 64);
            if (i >= off) w += t;
        }
        wsum[i] = w;
    }
    __syncthreads();
    int woff = wid ? wsum[wid - 1] : 0;
    if (i < nb) bs[i] = woff + incl - v;
}

__global__ __launch_bounds__(1024) void add_offsets(int* __restrict__ row_start,
                                                    const int* __restrict__ bs, int N, int E,
                                                    int* __restrict__ cursor) {
    int i = blockIdx.x * 1024 + threadIdx.x;
    if (i < N) {
        int s = row_start[i] + bs[blockIdx.x];
        row_start[i] = s;
        cursor[i] = s;
    }
    if (i == 0) row_start[N] = E;
}

// ---------------------------------------------------------------------------
// Fused fill: scatter edge src ids into grouped order (all layers)
// ---------------------------------------------------------------------------
__global__ void fill_all(const int* __restrict__ src0, const int* __restrict__ dst0,
                         const int* __restrict__ src1, const int* __restrict__ dst1,
                         const int* __restrict__ src2, const int* __restrict__ dst2,
                         int* __restrict__ cursor, int* __restrict__ ss) {
    int i = blockIdx.x * blockDim.x + threadIdx.x;
    if (i >= E_ALL) return;
    int k, s;
    if (i < NE0) {
        s = src0[i];
        k = dst0[i] * SPLIT0 + bucket0(s);
    } else if (i < NE0 + NE1) {
        int e = i - NE0;
        s = src1[e];
        k = RBASE1 + dst1[e];
    } else {
        int e = i - NE0 - NE1;
        s = src2[e];
        k = RBASE2 + dst2[e];
    }
    int p = atomicAdd(&cursor[k], 1);
    ss[p] = s;
}

// ---------------------------------------------------------------------------
// Layer-0 gather, pass P of SPLIT0.  One wave per dst row; F=256.
// P=0: write raw sums.  P=1,2: add (RMW).  P=3: add + normalize.
// ---------------------------------------------------------------------------
template <int P>
__global__ __launch_bounds__(256) void gather0_pass(const float* __restrict__ h,
                                                    const int* __restrict__ rs,
                                                    const int* __restrict__ ss,
                                                    float* __restrict__ out) {
    int lane = threadIdx.x & 63;
    int r = blockIdx.x * 4 + (threadIdx.x >> 6);
    if (r >= NL1) return;
    int s0 = rs[SPLIT0 * r + P];
    int s1 = rs[SPLIT0 * r + P + 1];

    const float* hp = h + (size_t)lane * 4;
    float4 acc = make_float4(0.f, 0.f, 0.f, 0.f);
    int e = s0;
    for (; e + 3 < s1; e += 4) {
        int ia = ss[e], ib = ss[e + 1], ic = ss[e + 2], id = ss[e + 3];
        float4 va = *(const float4*)(hp + (size_t)ia * F_IN);
        float4 vb = *(const float4*)(hp + (size_t)ib * F_IN);
        float4 vc = *(const float4*)(hp + (size_t)ic * F_IN);
        float4 vd = *(const float4*)(hp + (size_t)id * F_IN);
        acc.x += (va.x + vb.x) + (vc.x + vd.x);
        acc.y += (va.y + vb.y) + (vc.y + vd.y);
        acc.z += (va.z + vb.z) + (vc.z + vd.z);
        acc.w += (va.w + vb.w) + (vc.w + vd.w);
    }
    for (; e < s1; ++e) {
        int ia = ss[e];
        float4 va = *(const float4*)(hp + (size_t)ia * F_IN);
        acc.x += va.x; acc.y += va.y; acc.z += va.z; acc.w += va.w;
    }

    float* op = out + (size_t)r * F_IN + lane * 4;
    if constexpr (P > 0) {
        float4 prev = *(const float4*)op;
        acc.x += prev.x; acc.y += prev.y; acc.z += prev.z; acc.w += prev.w;
    }
    if constexpr (P == SPLIT0 - 1) {
        int tot = rs[SPLIT0 * r + SPLIT0] - rs[SPLIT0 * r];
        float inv = (tot > 0) ? 1.0f / (float)tot : 0.0f;
        acc.x *= inv; acc.y *= inv; acc.z *= inv; acc.w *= inv;
    }
    *(float4*)op = acc;
}

// ---------------------------------------------------------------------------
// Plain gather (F=128) with row base into the concatenated CSR.
// ---------------------------------------------------------------------------
__global__ __launch_bounds__(256) void gather128(const float* __restrict__ h,
                                                 const int* __restrict__ rs,
                                                 const int* __restrict__ ss,
                                                 float* __restrict__ out, int N, int rowbase) {
    int lane = threadIdx.x & 63;
    int r = blockIdx.x * 4 + (threadIdx.x >> 6);
    if (r >= N) return;
    int s0 = rs[rowbase + r], s1 = rs[rowbase + r + 1];
    int tot = s1 - s0;

    const float* hp = h + (size_t)lane * 2;
    float2 acc = make_float2(0.f, 0.f);
    int e = s0;
    for (; e + 3 < s1; e += 4) {
        int ia = ss[e], ib = ss[e + 1], ic = ss[e + 2], id = ss[e + 3];
        float2 va = *(const float2*)(hp + (size_t)ia * F_HID);
        float2 vb = *(const float2*)(hp + (size_t)ib * F_HID);
        float2 vc = *(const float2*)(hp + (size_t)ic * F_HID);
        float2 vd = *(const float2*)(hp + (size_t)id * F_HID);
        acc.x += (va.x + vb.x) + (vc.x + vd.x);
        acc.y += (va.y + vb.y) + (vc.y + vd.y);
    }
    for (; e < s1; ++e) {
        int ia = ss[e];
        float2 va = *(const float2*)(hp + (size_t)ia * F_HID);
        acc.x += va.x; acc.y += va.y;
    }
    float inv = (tot > 0) ? 1.0f / (float)tot : 0.0f;
    *(float2*)(out + (size_t)r * F_HID + lane * 2) = make_float2(acc.x * inv, acc.y * inv);
}

// ---------------------------------------------------------------------------
// Register-tiled fp32 GEMM for FOUT=128: C[N,128] = A[N,FIN] @ W[FIN,128] + b
// ---------------------------------------------------------------------------
template <int FIN, bool RELU>
__global__ __launch_bounds__(256) void linear128(const float* __restrict__ A,
                                                 const float* __restrict__ W,
                                                 const float* __restrict__ bias,
                                                 float* __restrict__ out, int N) {
    constexpr int KB = 32;
    __shared__ float as[KB][132];
    __shared__ float ws[KB][128];
    int tx = threadIdx.x & 15;
    int ty = threadIdx.x >> 4;
    int rbase = blockIdx.x * 128;

    float acc[8][8];
#pragma unroll
    for (int i = 0; i < 8; ++i)
#pragma unroll
        for (int j = 0; j < 8; ++j) acc[i][j] = 0.f;

    for (int k0 = 0; k0 < FIN; k0 += KB) {
#pragma unroll
        for (int f = threadIdx.x; f < 1024; f += 256) {
            int row = f >> 3;
            int kk = (f & 7) * 4;
            int gr = rbase + row;
            float4 v = (gr < N) ? *(const float4*)&A[(size_t)gr * FIN + k0 + kk]
                                : make_float4(0.f, 0.f, 0.f, 0.f);
            as[kk + 0][row] = v.x;
            as[kk + 1][row] = v.y;
            as[kk + 2][row] = v.z;
            as[kk + 3][row] = v.w;
        }
#pragma unroll
        for (int f = threadIdx.x; f < 1024; f += 256) {
            int c = (f & 31) * 4;
            int kk = f >> 5;
            *(float4*)&ws[kk][c] = *(const float4*)&W[(size_t)(k0 + kk) * 128 + c];
        }
        __syncthreads();
#pragma unroll
        for (int kk = 0; kk < KB; ++kk) {
            float4 a0 = *(const float4*)&as[kk][ty * 4];
            float4 a1 = *(const float4*)&as[kk][64 + ty * 4];
            float4 w0 = *(const float4*)&ws[kk][tx * 4];
            float4 w1 = *(const float4*)&ws[kk][64 + tx * 4];
            float a[8] = {a0.x, a0.y, a0.z, a0.w, a1.x, a1.y, a1.z, a1.w};
            float w[8] = {w0.x, w0.y, w0.z, w0.w, w1.x, w1.y, w1.z, w1.w};
#pragma unroll
            for (int i = 0; i < 8; ++i)
#pragma unroll
                for (int j = 0; j < 8; ++j) acc[i][j] += a[i] * w[j];
        }
        __syncthreads();
    }

    float4 bb0 = *(const float4*)&bias[tx * 4];
    float4 bb1 = *(const float4*)&bias[64 + tx * 4];
#pragma unroll
    for (int i = 0; i < 8; ++i) {
        int row = rbase + (i < 4 ? ty * 4 + i : 64 + ty * 4 + (i - 4));
        if (row < N) {
            float4 o0 = make_float4(acc[i][0] + bb0.x, acc[i][1] + bb0.y,
                                    acc[i][2] + bb0.z, acc[i][3] + bb0.w);
            float4 o1 = make_float4(acc[i][4] + bb1.x, acc[i][5] + bb1.y,
                                    acc[i][6] + bb1.z, acc[i][7] + bb1.w);
            if (RELU) {
                o0.x = fmaxf(o0.x, 0.f); o0.y = fmaxf(o0.y, 0.f);
                o0.z = fmaxf(o0.z, 0.f); o0.w = fmaxf(o0.w, 0.f);
                o1.x = fmaxf(o1.x, 0.f); o1.y = fmaxf(o1.y, 0.f);
                o1.z = fmaxf(o1.z, 0.f); o1.w = fmaxf(o1.w, 0.f);
            }
            *(float4*)&out[(size_t)row * 128 + tx * 4] = o0;
            *(float4*)&out[(size_t)row * 128 + 64 + tx * 4] = o1;
        }
    }
}

// ---------------------------------------------------------------------------
// Small linear for the 47-col output layer (one block = 8 rows).
// ---------------------------------------------------------------------------
template <int FIN, int FOUT, int CTH, int RPB, bool RELU>
__global__ __launch_bounds__(256) void linear_kernel(const float* __restrict__ in,
                                                     const float* __restrict__ W,
                                                     const float* __restrict__ b,
                                                     float* __restrict__ out, int N) {
    constexpr int RG = 256 / CTH;
    constexpr int RPT = RPB / RG;
    __shared__ __align__(16) float rows[RPB][FIN];
    int rbase = blockIdx.x * RPB;

    for (int idx = threadIdx.x * 4; idx < RPB * FIN; idx += 256 * 4) {
        *(float4*)&rows[0][idx] = *(const float4*)&in[(size_t)rbase * FIN + idx];
    }
    __syncthreads();

    int j = threadIdx.x % CTH;
    int rg = threadIdx.x / CTH;
    if (j < FOUT) {
        float acc[RPT];
#pragma unroll
        for (int r = 0; r < RPT; ++r) acc[r] = 0.f;
#pragma unroll 8
        for (int k = 0; k < FIN; ++k) {
            float w = W[k * FOUT + j];
#pragma unroll
            for (int r = 0; r < RPT; ++r)
                acc[r] += rows[rg * RPT + r][k] * w;
        }
        float bb = b[j];
#pragma unroll
        for (int r = 0; r < RPT; ++r) {
            float v = acc[r] + bb;
            if (RELU) v = fmaxf(v, 0.f);
            out[(size_t)(rbase + rg * RPT + r) * FOUT + j] = v;
        }
    }
}

// ---------------------------------------------------------------------------

static inline size_t align256(size_t x) { return (x + 255) & ~size_t(255); }

extern "C" void kernel_launch(void* const* d_in, const int* in_sizes, int n_in,
                              void* d_out, int out_size, void* d_ws, size_t ws_size,
                              hipStream_t stream) {
    const float* features = (const float*)d_in[0];
    const int*   src0     = (const int*)d_in[1];
    const int*   dst0     = (const int*)d_in[2];
    const int*   src1     = (const int*)d_in[3];
    const int*   dst1     = (const int*)d_in[4];
    const int*   src2     = (const int*)d_in[5];
    const int*   dst2     = (const int*)d_in[6];
    const float* W1       = (const float*)d_in[7];
    const float* b1       = (const float*)d_in[8];
    const float* W2       = (const float*)d_in[9];
    const float* b2       = (const float*)d_in[10];
    const float* W3       = (const float*)d_in[11];
    const float* b3       = (const float*)d_in[12];
    float* out = (float*)d_out;

    char* p = (char*)d_ws;
    size_t off = 0;
    auto alloc = [&](size_t bytes) {
        char* r = p + off;
        off += align256(bytes);
        return r;
    };
    float* mean0 = (float*)alloc(sizeof(float) * (size_t)NL1 * F_IN);
    float* h1    = (float*)alloc(sizeof(float) * (size_t)NL1 * F_HID);
    float* mean1 = (float*)alloc(sizeof(float) * (size_t)NL2 * F_HID);
    float* h2    = (float*)alloc(sizeof(float) * (size_t)NL2 * F_HID);
    float* mean2 = (float*)alloc(sizeof(float) * (size_t)NL3 * F_HID);
    int* cnt = (int*)alloc(sizeof(int) * NROWS);
    int* rs  = (int*)alloc(sizeof(int) * (NROWS + 1));
    int* cur = (int*)alloc(sizeof(int) * NROWS);
    int* bs  = (int*)alloc(sizeof(int) * 1024);
    int* ss  = (int*)alloc(sizeof(int) * E_ALL);
    (void)ws_size;

    // ---- Fused CSR build over all layers ----
    hipMemsetAsync(cnt, 0, sizeof(int) * NROWS, stream);
    histogram_all<<<(E_ALL + 255) / 256, 256, 0, stream>>>(src0, dst0, dst1, dst2, cnt);
    int nb = (NROWS + 1023) / 1024;
    scan_block<<<nb, 1024, 0, stream>>>(cnt, NROWS, rs, bs);
    scan_totals<<<1, 1024, 0, stream>>>(bs, nb);
    add_offsets<<<nb, 1024, 0, stream>>>(rs, bs, NROWS, E_ALL, cur);
    fill_all<<<(E_ALL + 255) / 256, 256, 0, stream>>>(src0, dst0, src1, dst1, src2, dst2,
                                                      cur, ss);

    // ---- Layer 0 -> 1: 4-pass L3-blocked gather, then GEMM ----
    gather0_pass<0><<<NL1 / 4, 256, 0, stream>>>(features, rs, ss, mean0);
    gather0_pass<1><<<NL1 / 4, 256, 0, stream>>>(features, rs, ss, mean0);
    gather0_pass<2><<<NL1 / 4, 256, 0, stream>>>(features, rs, ss, mean0);
    gather0_pass<3><<<NL1 / 4, 256, 0, stream>>>(features, rs, ss, mean0);
    linear128<F_IN, true><<<(NL1 + 127) / 128, 256, 0, stream>>>(mean0, W1, b1, h1, NL1);

    // ---- Layer 1 -> 2 ----
    gather128<<<NL2 / 4, 256, 0, stream>>>(h1, rs, ss, mean1, NL2, RBASE1);
    linear128<F_HID, true><<<(NL2 + 127) / 128, 256, 0, stream>>>(mean1, W2, b2, h2, NL2);

    // ---- Layer 2 -> 3 ----
    gather128<<<NL3 / 4, 256, 0, stream>>>(h2, rs, ss, mean2, NL3, RBASE2);
    linear_kernel<F_HID, F_OUT, 64, 8, false><<<NL3 / 8, 256, 0, stream>>>(mean2, W3, b3, out, NL3);
}

// Round 5
// 452.636 us; speedup vs baseline: 1.0945x; 1.0945x over previous
//
#include <hip/hip_runtime.h>

// Problem constants (from reference)
#define NL0 300000
#define NL1 60000
#define NL2 15000
#define NL3 4000
#define NE0 960000
#define NE1 240000
#define NE2 64000
#define E_ALL (NE0 + NE1 + NE2)
#define F_IN 256
#define F_HID 128
#define F_OUT 47

// Concatenated CSR row layout:
//   [0, 60000)        : layer0 dst
//   [60000, 75000)    : layer1 dst
//   [75000, 79000)    : layer2 dst
#define RBASE1 NL1
#define RBASE2 (NL1 + NL2)
#define NROWS (NL1 + NL2 + NL3)

// ---------------------------------------------------------------------------
// Wave-wide (64-lane) inclusive scan
// ---------------------------------------------------------------------------
__device__ inline int wave_incl_scan(int v) {
    int lane = threadIdx.x & 63;
#pragma unroll
    for (int off = 1; off < 64; off <<= 1) {
        int t = __shfl_up(v, off, 64);
        if (lane >= off) v += t;
    }
    return v;
}

// ---------------------------------------------------------------------------
// Fused histogram over all three layers' edges
// ---------------------------------------------------------------------------
__global__ void histogram_all(const int* __restrict__ dst0, const int* __restrict__ dst1,
                              const int* __restrict__ dst2, int* __restrict__ cnt) {
    int i = blockIdx.x * blockDim.x + threadIdx.x;
    if (i >= E_ALL) return;
    int k;
    if (i < NE0) {
        k = dst0[i];
    } else if (i < NE0 + NE1) {
        k = RBASE1 + dst1[i - NE0];
    } else {
        k = RBASE2 + dst2[i - NE0 - NE1];
    }
    atomicAdd(&cnt[k], 1);
}

// ---------------------------------------------------------------------------
// Exclusive scan over NROWS counters (chunked: per-1024 scan + totals + add)
// ---------------------------------------------------------------------------
__global__ __launch_bounds__(1024) void scan_block(const int* __restrict__ cnt, int N,
                                                   int* __restrict__ row_start,
                                                   int* __restrict__ blocksum) {
    __shared__ int wsum[16];
    int i = blockIdx.x * 1024 + threadIdx.x;
    int lane = threadIdx.x & 63, wid = threadIdx.x >> 6;
    int v = (i < N) ? cnt[i] : 0;
    int incl = wave_incl_scan(v);
    if (lane == 63) wsum[wid] = incl;
    __syncthreads();
    if (threadIdx.x < 16) {
        int w = wsum[threadIdx.x];
#pragma unroll
        for (int off = 1; off < 16; off <<= 1) {
            int t = __shfl_up(w, off, 64);
            if ((int)threadIdx.x >= off) w += t;
        }
        wsum[threadIdx.x] = w;
    }
    __syncthreads();
    int woff = wid ? wsum[wid - 1] : 0;
    if (i < N) row_start[i] = woff + incl - v;
    if (threadIdx.x == 0) blocksum[blockIdx.x] = wsum[15];
}

__global__ __launch_bounds__(1024) void scan_totals(int* __restrict__ bs, int nb) {
    __shared__ int wsum[16];
    int i = threadIdx.x;
    int lane = i & 63, wid = i >> 6;
    int v = (i < nb) ? bs[i] : 0;
    int incl = wave_incl_scan(v);
    if (lane == 63) wsum[wid] = incl;
    __syncthreads();
    if (i < 16) {
        int w = wsum[i];
#pragma unroll
        for (int off = 1; off < 16; off <<= 1) {
            int t = __shfl_up(w, off, 64);
            if (i >= off) w += t;
        }
        wsum[i] = w;
    }
    __syncthreads();
    int woff = wid ? wsum[wid - 1] : 0;
    if (i < nb) bs[i] = woff + incl - v;
}

__global__ __launch_bounds__(1024) void add_offsets(int* __restrict__ row_start,
                                                    const int* __restrict__ bs, int N, int E,
                                                    int* __restrict__ cursor) {
    int i = blockIdx.x * 1024 + threadIdx.x;
    if (i < N) {
        int s = row_start[i] + bs[blockIdx.x];
        row_start[i] = s;
        cursor[i] = s;
    }
    if (i == 0) row_start[N] = E;
}

// ---------------------------------------------------------------------------
// Fused fill: scatter edge src ids into dst-grouped order (all layers)
// ---------------------------------------------------------------------------
__global__ void fill_all(const int* __restrict__ src0, const int* __restrict__ dst0,
                         const int* __restrict__ src1, const int* __restrict__ dst1,
                         const int* __restrict__ src2, const int* __restrict__ dst2,
                         int* __restrict__ cursor, int* __restrict__ ss) {
    int i = blockIdx.x * blockDim.x + threadIdx.x;
    if (i >= E_ALL) return;
    int k, s;
    if (i < NE0) {
        s = src0[i];
        k = dst0[i];
    } else if (i < NE0 + NE1) {
        int e = i - NE0;
        s = src1[e];
        k = RBASE1 + dst1[e];
    } else {
        int e = i - NE0 - NE1;
        s = src2[e];
        k = RBASE2 + dst2[e];
    }
    int p = atomicAdd(&cursor[k], 1);
    ss[p] = s;
}

// ---------------------------------------------------------------------------
// Layer-0 gather (F=256): one wave per dst row, 8-deep unrolled float4 loads.
// ---------------------------------------------------------------------------
__global__ __launch_bounds__(256) void gather256(const float* __restrict__ h,
                                                 const int* __restrict__ rs,
                                                 const int* __restrict__ ss,
                                                 float* __restrict__ out) {
    int lane = threadIdx.x & 63;
    int r = blockIdx.x * 4 + (threadIdx.x >> 6);
    if (r >= NL1) return;
    int s0 = rs[r], s1 = rs[r + 1];
    int tot = s1 - s0;

    const float* hp = h + (size_t)lane * 4;
    float4 acc0 = make_float4(0.f, 0.f, 0.f, 0.f);
    float4 acc1 = make_float4(0.f, 0.f, 0.f, 0.f);
    int e = s0;
    for (; e + 7 < s1; e += 8) {
        int i0 = ss[e], i1 = ss[e + 1], i2 = ss[e + 2], i3 = ss[e + 3];
        int i4 = ss[e + 4], i5 = ss[e + 5], i6 = ss[e + 6], i7 = ss[e + 7];
        float4 v0 = *(const float4*)(hp + (size_t)i0 * F_IN);
        float4 v1 = *(const float4*)(hp + (size_t)i1 * F_IN);
        float4 v2 = *(const float4*)(hp + (size_t)i2 * F_IN);
        float4 v3 = *(const float4*)(hp + (size_t)i3 * F_IN);
        float4 v4 = *(const float4*)(hp + (size_t)i4 * F_IN);
        float4 v5 = *(const float4*)(hp + (size_t)i5 * F_IN);
        float4 v6 = *(const float4*)(hp + (size_t)i6 * F_IN);
        float4 v7 = *(const float4*)(hp + (size_t)i7 * F_IN);
        acc0.x += (v0.x + v1.x) + (v2.x + v3.x);
        acc0.y += (v0.y + v1.y) + (v2.y + v3.y);
        acc0.z += (v0.z + v1.z) + (v2.z + v3.z);
        acc0.w += (v0.w + v1.w) + (v2.w + v3.w);
        acc1.x += (v4.x + v5.x) + (v6.x + v7.x);
        acc1.y += (v4.y + v5.y) + (v6.y + v7.y);
        acc1.z += (v4.z + v5.z) + (v6.z + v7.z);
        acc1.w += (v4.w + v5.w) + (v6.w + v7.w);
    }
    for (; e + 1 < s1; e += 2) {
        int i0 = ss[e], i1 = ss[e + 1];
        float4 v0 = *(const float4*)(hp + (size_t)i0 * F_IN);
        float4 v1 = *(const float4*)(hp + (size_t)i1 * F_IN);
        acc0.x += v0.x + v1.x; acc0.y += v0.y + v1.y;
        acc0.z += v0.z + v1.z; acc0.w += v0.w + v1.w;
    }
    if (e < s1) {
        int i0 = ss[e];
        float4 v0 = *(const float4*)(hp + (size_t)i0 * F_IN);
        acc0.x += v0.x; acc0.y += v0.y; acc0.z += v0.z; acc0.w += v0.w;
    }
    float inv = (tot > 0) ? 1.0f / (float)tot : 0.0f;
    float4 o = make_float4((acc0.x + acc1.x) * inv, (acc0.y + acc1.y) * inv,
                           (acc0.z + acc1.z) * inv, (acc0.w + acc1.w) * inv);
    *(float4*)(out + (size_t)r * F_IN + lane * 4) = o;
}

// ---------------------------------------------------------------------------
// Gather (F=128) with row base into the concatenated CSR.
// ---------------------------------------------------------------------------
__global__ __launch_bounds__(256) void gather128(const float* __restrict__ h,
                                                 const int* __restrict__ rs,
                                                 const int* __restrict__ ss,
                                                 float* __restrict__ out, int N, int rowbase) {
    int lane = threadIdx.x & 63;
    int r = blockIdx.x * 4 + (threadIdx.x >> 6);
    if (r >= N) return;
    int s0 = rs[rowbase + r], s1 = rs[rowbase + r + 1];
    int tot = s1 - s0;

    const float* hp = h + (size_t)lane * 2;
    float2 acc0 = make_float2(0.f, 0.f);
    float2 acc1 = make_float2(0.f, 0.f);
    int e = s0;
    for (; e + 7 < s1; e += 8) {
        int i0 = ss[e], i1 = ss[e + 1], i2 = ss[e + 2], i3 = ss[e + 3];
        int i4 = ss[e + 4], i5 = ss[e + 5], i6 = ss[e + 6], i7 = ss[e + 7];
        float2 v0 = *(const float2*)(hp + (size_t)i0 * F_HID);
        float2 v1 = *(const float2*)(hp + (size_t)i1 * F_HID);
        float2 v2 = *(const float2*)(hp + (size_t)i2 * F_HID);
        float2 v3 = *(const float2*)(hp + (size_t)i3 * F_HID);
        float2 v4 = *(const float2*)(hp + (size_t)i4 * F_HID);
        float2 v5 = *(const float2*)(hp + (size_t)i5 * F_HID);
        float2 v6 = *(const float2*)(hp + (size_t)i6 * F_HID);
        float2 v7 = *(const float2*)(hp + (size_t)i7 * F_HID);
        acc0.x += (v0.x + v1.x) + (v2.x + v3.x);
        acc0.y += (v0.y + v1.y) + (v2.y + v3.y);
        acc1.x += (v4.x + v5.x) + (v6.x + v7.x);
        acc1.y += (v4.y + v5.y) + (v6.y + v7.y);
    }
    for (; e < s1; ++e) {
        int i0 = ss[e];
        float2 v0 = *(const float2*)(hp + (size_t)i0 * F_HID);
        acc0.x += v0.x; acc0.y += v0.y;
    }
    float inv = (tot > 0) ? 1.0f / (float)tot : 0.0f;
    *(float2*)(out + (size_t)r * F_HID + lane * 2) =
        make_float2((acc0.x + acc1.x) * inv, (acc0.y + acc1.y) * inv);
}

// ---------------------------------------------------------------------------
// Register-tiled fp32 GEMM for FOUT=128: C[N,128] = A[N,FIN] @ W[FIN,128] + b
// A-tile k-major with pad 136 (2-way banks on staging stores = free; rows of
// 544 B keep ds_read_b128 alignment).
// ---------------------------------------------------------------------------
template <int FIN, bool RELU>
__global__ __launch_bounds__(256) void linear128(const float* __restrict__ A,
                                                 const float* __restrict__ W,
                                                 const float* __restrict__ bias,
                                                 float* __restrict__ out, int N) {
    constexpr int KB = 32;
    __shared__ float as[KB][136];
    __shared__ float ws[KB][128];
    int tx = threadIdx.x & 15;
    int ty = threadIdx.x >> 4;
    int rbase = blockIdx.x * 128;

    float acc[8][8];
#pragma unroll
    for (int i = 0; i < 8; ++i)
#pragma unroll
        for (int j = 0; j < 8; ++j) acc[i][j] = 0.f;

    for (int k0 = 0; k0 < FIN; k0 += KB) {
#pragma unroll
        for (int f = threadIdx.x; f < 1024; f += 256) {
            int row = f >> 3;
            int kk = (f & 7) * 4;
            int gr = rbase + row;
            float4 v = (gr < N) ? *(const float4*)&A[(size_t)gr * FIN + k0 + kk]
                                : make_float4(0.f, 0.f, 0.f, 0.f);
            as[kk + 0][row] = v.x;
            as[kk + 1][row] = v.y;
            as[kk + 2][row] = v.z;
            as[kk + 3][row] = v.w;
        }
#pragma unroll
        for (int f = threadIdx.x; f < 1024; f += 256) {
            int c = (f & 31) * 4;
            int kk = f >> 5;
            *(float4*)&ws[kk][c] = *(const float4*)&W[(size_t)(k0 + kk) * 128 + c];
        }
        __syncthreads();
#pragma unroll
        for (int kk = 0; kk < KB; ++kk) {
            float4 a0 = *(const float4*)&as[kk][ty * 4];
            float4 a1 = *(const float4*)&as[kk][64 + ty * 4];
            float4 w0 = *(const float4*)&ws[kk][tx * 4];
            float4 w1 = *(const float4*)&ws[kk][64 + tx * 4];
            float a[8] = {a0.x, a0.y, a0.z, a0.w, a1.x, a1.y, a1.z, a1.w};
            float w[8] = {w0.x, w0.y, w0.z, w0.w, w1.x, w1.y, w1.z, w1.w};
#pragma unroll
            for (int i = 0; i < 8; ++i)
#pragma unroll
                for (int j = 0; j < 8; ++j) acc[i][j] += a[i] * w[j];
        }
        __syncthreads();
    }

    float4 bb0 = *(const float4*)&bias[tx * 4];
    float4 bb1 = *(const float4*)&bias[64 + tx * 4];
#pragma unroll
    for (int i = 0; i < 8; ++i) {
        int row = rbase + (i < 4 ? ty * 4 + i : 64 + ty * 4 + (i - 4));
        if (row < N) {
            float4 o0 = make_float4(acc[i][0] + bb0.x, acc[i][1] + bb0.y,
                                    acc[i][2] + bb0.z, acc[i][3] + bb0.w);
            float4 o1 = make_float4(acc[i][4] + bb1.x, acc[i][5] + bb1.y,
                                    acc[i][6] + bb1.z, acc[i][7] + bb1.w);
            if (RELU) {
                o0.x = fmaxf(o0.x, 0.f); o0.y = fmaxf(o0.y, 0.f);
                o0.z = fmaxf(o0.z, 0.f); o0.w = fmaxf(o0.w, 0.f);
                o1.x = fmaxf(o1.x, 0.f); o1.y = fmaxf(o1.y, 0.f);
                o1.z = fmaxf(o1.z, 0.f); o1.w = fmaxf(o1.w, 0.f);
            }
            *(float4*)&out[(size_t)row * 128 + tx * 4] = o0;
            *(float4*)&out[(size_t)row * 128 + 64 + tx * 4] = o1;
        }
    }
}

// ---------------------------------------------------------------------------
// Small linear for the 47-col output layer (one block = 8 rows).
// ---------------------------------------------------------------------------
template <int FIN, int FOUT, int CTH, int RPB, bool RELU>
__global__ __launch_bounds__(256) void linear_kernel(const float* __restrict__ in,
                                                     const float* __restrict__ W,
                                                     const float* __restrict__ b,
                                                     float* __restrict__ out, int N) {
    constexpr int RG = 256 / CTH;
    constexpr int RPT = RPB / RG;
    __shared__ __align__(16) float rows[RPB][FIN];
    int rbase = blockIdx.x * RPB;

    for (int idx = threadIdx.x * 4; idx < RPB * FIN; idx += 256 * 4) {
        *(float4*)&rows[0][idx] = *(const float4*)&in[(size_t)rbase * FIN + idx];
    }
    __syncthreads();

    int j = threadIdx.x % CTH;
    int rg = threadIdx.x / CTH;
    if (j < FOUT) {
        float acc[RPT];
#pragma unroll
        for (int r = 0; r < RPT; ++r) acc[r] = 0.f;
#pragma unroll 8
        for (int k = 0; k < FIN; ++k) {
            float w = W[k * FOUT + j];
#pragma unroll
            for (int r = 0; r < RPT; ++r)
                acc[r] += rows[rg * RPT + r][k] * w;
        }
        float bb = b[j];
#pragma unroll
        for (int r = 0; r < RPT; ++r) {
            float v = acc[r] + bb;
            if (RELU) v = fmaxf(v, 0.f);
            out[(size_t)(rbase + rg * RPT + r) * FOUT + j] = v;
        }
    }
}

// ---------------------------------------------------------------------------

static inline size_t align256(size_t x) { return (x + 255) & ~size_t(255); }

extern "C" void kernel_launch(void* const* d_in, const int* in_sizes, int n_in,
                              void* d_out, int out_size, void* d_ws, size_t ws_size,
                              hipStream_t stream) {
    const float* features = (const float*)d_in[0];
    const int*   src0     = (const int*)d_in[1];
    const int*   dst0     = (const int*)d_in[2];
    const int*   src1     = (const int*)d_in[3];
    const int*   dst1     = (const int*)d_in[4];
    const int*   src2     = (const int*)d_in[5];
    const int*   dst2     = (const int*)d_in[6];
    const float* W1       = (const float*)d_in[7];
    const float* b1       = (const float*)d_in[8];
    const float* W2       = (const float*)d_in[9];
    const float* b2       = (const float*)d_in[10];
    const float* W3       = (const float*)d_in[11];
    const float* b3       = (const float*)d_in[12];
    float* out = (float*)d_out;

    char* p = (char*)d_ws;
    size_t off = 0;
    auto alloc = [&](size_t bytes) {
        char* r = p + off;
        off += align256(bytes);
        return r;
    };
    float* mean0 = (float*)alloc(sizeof(float) * (size_t)NL1 * F_IN);
    float* h1    = (float*)alloc(sizeof(float) * (size_t)NL1 * F_HID);
    float* mean1 = (float*)alloc(sizeof(float) * (size_t)NL2 * F_HID);
    float* h2    = (float*)alloc(sizeof(float) * (size_t)NL2 * F_HID);
    float* mean2 = (float*)alloc(sizeof(float) * (size_t)NL3 * F_HID);
    int* cnt = (int*)alloc(sizeof(int) * NROWS);
    int* rs  = (int*)alloc(sizeof(int) * (NROWS + 1));
    int* cur = (int*)alloc(sizeof(int) * NROWS);
    int* bs  = (int*)alloc(sizeof(int) * 1024);
    int* ss  = (int*)alloc(sizeof(int) * E_ALL);
    (void)ws_size;

    // ---- Fused CSR build over all layers ----
    hipMemsetAsync(cnt, 0, sizeof(int) * NROWS, stream);
    histogram_all<<<(E_ALL + 255) / 256, 256, 0, stream>>>(dst0, dst1, dst2, cnt);
    int nb = (NROWS + 1023) / 1024;
    scan_block<<<nb, 1024, 0, stream>>>(cnt, NROWS, rs, bs);
    scan_totals<<<1, 1024, 0, stream>>>(bs, nb);
    add_offsets<<<nb, 1024, 0, stream>>>(rs, bs, NROWS, E_ALL, cur);
    fill_all<<<(E_ALL + 255) / 256, 256, 0, stream>>>(src0, dst0, src1, dst1, src2, dst2,
                                                      cur, ss);

    // ---- Layer 0 -> 1 ----
    gather256<<<NL1 / 4, 256, 0, stream>>>(features, rs, ss, mean0);
    linear128<F_IN, true><<<(NL1 + 127) / 128, 256, 0, stream>>>(mean0, W1, b1, h1, NL1);

    // ---- Layer 1 -> 2 ----
    gather128<<<NL2 / 4, 256, 0, stream>>>(h1, rs, ss, mean1, NL2, RBASE1);
    linear128<F_HID, true><<<(NL2 + 127) / 128, 256, 0, stream>>>(mean1, W2, b2, h2, NL2);

    // ---- Layer 2 -> 3 ----
    gather128<<<NL3 / 4, 256, 0, stream>>>(h2, rs, ss, mean2, NL3, RBASE2);
    linear_kernel<F_HID, F_OUT, 64, 8, false><<<NL3 / 8, 256, 0, stream>>>(mean2, W3, b3, out, NL3);
}